// Round 15
// baseline (761.172 us; speedup 1.0000x reference)
//
#include <hip/hip_runtime.h>
#include <hip/hip_bf16.h>

#define B_ROWS   524288
#define MEL_BINS 128
#define DIM      64
#define KCODES   128
// 3-term bf16-split screen error ~1e-3; EPS gives ~60x margin (R12-proven).
#define EPS_SCREEN 0.0625f

typedef short short8 __attribute__((ext_vector_type(8)));
typedef float f32x4  __attribute__((ext_vector_type(4)));
typedef unsigned int uint4v __attribute__((ext_vector_type(4)));

// ---------------- workspace layout (floats) ----------------
#define WS_WT 0
#define WS_N0 (WS_WT + MEL_BINS*DIM)        // 8192
#define WS_N1 (WS_N0 + KCODES)              // 8320
#define WS_T0 (WS_N1 + KCODES)              // 8448
#define WS_T1 (WS_T0 + KCODES*MEL_BINS)     // 24832
#define WS_TOT (WS_T1 + KCODES*MEL_BINS)    // 41216 floats

__device__ __forceinline__ float np_pairwise64_sq(const float* v) {
#pragma clang fp contract(off)
    float r0 = v[0]*v[0], r1 = v[1]*v[1], r2 = v[2]*v[2], r3 = v[3]*v[3];
    float r4 = v[4]*v[4], r5 = v[5]*v[5], r6 = v[6]*v[6], r7 = v[7]*v[7];
#pragma unroll
    for (int i = 8; i < 64; i += 8) {
        r0 += v[i+0]*v[i+0]; r1 += v[i+1]*v[i+1];
        r2 += v[i+2]*v[i+2]; r3 += v[i+3]*v[i+3];
        r4 += v[i+4]*v[i+4]; r5 += v[i+5]*v[i+5];
        r6 += v[i+6]*v[i+6]; r7 += v[i+7]*v[i+7];
    }
    return ((r0 + r1) + (r2 + r3)) + ((r4 + r5) + (r6 + r7));
}

__global__ __launch_bounds__(256) void rvq_precomp(
    const float* __restrict__ W_in, const float* __restrict__ cb0,
    const float* __restrict__ cb1, const float* __restrict__ W_out,
    float* __restrict__ ws)
{
#pragma clang fp contract(off)
    float* WT = ws + WS_WT;
    float* n0 = ws + WS_N0;
    float* n1 = ws + WS_N1;
    float* T0 = ws + WS_T0;
    float* T1 = ws + WS_T1;

    int tid = blockIdx.x * 256 + threadIdx.x;
    if (tid < 16384) {
        int i = tid >> 7, m = tid & 127;
        double a = 0.0;
        for (int d = 0; d < DIM; ++d)
            a = fma((double)cb0[i*DIM + d], (double)W_out[m*DIM + d], a);
        T0[tid] = (float)a;
    } else if (tid < 32768) {
        int t = tid - 16384;
        int i = t >> 7, m = t & 127;
        double a = 0.0;
        for (int d = 0; d < DIM; ++d)
            a = fma((double)cb1[i*DIM + d], (double)W_out[m*DIM + d], a);
        T1[t] = (float)a;
    } else if (tid < 40960) {                // WT[j][d] = W_in[d][j]
        int t = tid - 32768;
        int j = t >> 6, d = t & 63;
        WT[t] = W_in[d*MEL_BINS + j];
    } else if (tid < 41216) {                // n0 / n1 (exact np pairwise)
        int t = tid - 40960;
        const float* cb = (t & 128) ? cb1 : cb0;
        float*       nn = (t & 128) ? n1  : n0;
        int k = t & 127;
        nn[k] = np_pairwise64_sq(cb + k*DIM);
    }
}

// round-to-nearest-even f32 -> bf16 bits
__device__ __forceinline__ unsigned rne16(float x) {
    unsigned u = __float_as_uint(x);
    return (u + 0x7fffu + ((u >> 16) & 1u)) >> 16;
}

// 3-term bf16-split MFMA screen (R12-proven memory structure: 32-bit packed
// hi|lo LDS staging, single read pass) + running-threshold candidate bitmap
// + exact np re-eval (ascending k, strict < == np.argmin). Candidate set
// provably contains the np argmin: when k* is processed, the running min
// includes it, so v_k* <= rmin + 2e <= rmin + EPS.
__device__ __forceinline__ int vq_step(const float* __restrict__ cbg,
                                       const float* __restrict__ ng,
                                       unsigned* tab,
                                       float (&z)[64], float sum_rr,
                                       int tid)
{
#pragma clang fp contract(off)
    const int lane = tid & 63;
    const int c  = lane & 15;
    const int g  = lane >> 4;
    const bool gb0 = (lane & 16) != 0;
    const bool gb1 = (lane & 32) != 0;
    const int r3  = lane & 3;
    const int sgl = ((lane >> 2) & 3) << 4;      // source lane for bitmap pull
    const unsigned bit0 = 1u << c, bit1 = 1u << (16 + c);

    // ---- stage codebook bf16 splits into LDS: packed (hi16|lo16) per [k][d^swz]
    __syncthreads();
    for (int e = tid; e < 8192; e += 256) {
        int k = e >> 6, d = e & 63;
        float v = cbg[e];
        unsigned hb = rne16(v);
        float hf = __uint_as_float(hb << 16);
        unsigned lb = rne16(v - hf);
        tab[(k << 6) | (d ^ ((k & 7) << 3))] = (hb << 16) | lb;
    }
    float nv[8];
#pragma unroll
    for (int n = 0; n < 8; ++n) nv[n] = ng[(n << 4) | c];
    __syncthreads();

    unsigned mybm[4] = {0u, 0u, 0u, 0u};

    for (int T = 0; T < 4; ++T) {                // 16-row tiles of the wave's 64 rows
        const int srcl = ((T << 4) | c) << 2;    // owner lane of A-row (l&15)

        // ---- A fragments (zh, zl) via bpermute from owner lanes (R12 verbatim)
        short8 Ah[2], Al[2];
#pragma unroll
        for (int ks = 0; ks < 2; ++ks) {
            unsigned hq[4], lq[4];
#pragma unroll
            for (int j = 0; j < 8; ++j) {
                int p0 = __builtin_amdgcn_ds_bpermute(srcl, __float_as_int(z[32*ks + j]));
                int p1 = __builtin_amdgcn_ds_bpermute(srcl, __float_as_int(z[32*ks + 8 + j]));
                int p2 = __builtin_amdgcn_ds_bpermute(srcl, __float_as_int(z[32*ks + 16 + j]));
                int p3 = __builtin_amdgcn_ds_bpermute(srcl, __float_as_int(z[32*ks + 24 + j]));
                float av = __int_as_float(gb1 ? (gb0 ? p3 : p2) : (gb0 ? p1 : p0));
                unsigned hb = rne16(av);
                float hf = __uint_as_float(hb << 16);
                unsigned lb = rne16(av - hf);
                if ((j & 1) == 0) { hq[j >> 1] = hb;       lq[j >> 1] = lb; }
                else              { hq[j >> 1] |= hb << 16; lq[j >> 1] |= lb << 16; }
            }
            uint4v hv = {hq[0], hq[1], hq[2], hq[3]};
            uint4v lv = {lq[0], lq[1], lq[2], lq[3]};
            Ah[ks] = __builtin_bit_cast(short8, hv);
            Al[ks] = __builtin_bit_cast(short8, lv);
        }

        // ---- single pass over 8 N-tiles: transient C, running threshold ----
        float rmin[4] = {3.4e38f, 3.4e38f, 3.4e38f, 3.4e38f};
        unsigned bm[4][4] = {};
#pragma unroll
        for (int n = 0; n < 8; ++n) {
            const int kcol = (n << 4) | c;
            const int swz = (kcol & 7) << 3;
            f32x4 C = (f32x4){0.f, 0.f, 0.f, 0.f};
#pragma unroll
            for (int ks = 0; ks < 2; ++ks) {
                const int d0 = 32*ks + (g << 3);
                const unsigned* p = &tab[(kcol << 6) | (d0 ^ swz)];
                uint4v w0 = *(const uint4v*)p;
                uint4v w1 = *(const uint4v*)(p + 4);
                unsigned h0 = (w0.x >> 16) | (w0.y & 0xffff0000u);
                unsigned h1 = (w0.z >> 16) | (w0.w & 0xffff0000u);
                unsigned h2 = (w1.x >> 16) | (w1.y & 0xffff0000u);
                unsigned h3 = (w1.z >> 16) | (w1.w & 0xffff0000u);
                unsigned l0 = (w0.x & 0xffffu) | (w0.y << 16);
                unsigned l1 = (w0.z & 0xffffu) | (w0.w << 16);
                unsigned l2 = (w1.x & 0xffffu) | (w1.y << 16);
                unsigned l3 = (w1.z & 0xffffu) | (w1.w << 16);
                uint4v bhv = {h0, h1, h2, h3};
                uint4v blv = {l0, l1, l2, l3};
                short8 Bh = __builtin_bit_cast(short8, bhv);
                short8 Bl = __builtin_bit_cast(short8, blv);
                C = __builtin_amdgcn_mfma_f32_16x16x32_bf16(Ah[ks], Bh, C, 0, 0, 0);
                C = __builtin_amdgcn_mfma_f32_16x16x32_bf16(Ah[ks], Bl, C, 0, 0, 0);
                C = __builtin_amdgcn_mfma_f32_16x16x32_bf16(Al[ks], Bh, C, 0, 0, 0);
            }
            float v4[4];
#pragma unroll
            for (int i = 0; i < 4; ++i) {
                v4[i] = fmaf(-2.f, C[i], nv[n]);
                rmin[i] = fminf(rmin[i], v4[i]);
            }
#pragma unroll
            for (int i = 0; i < 4; ++i) {        // group-tighten (includes step n)
                float m = rmin[i];
                m = fminf(m, __shfl_xor(m, 1));
                m = fminf(m, __shfl_xor(m, 2));
                m = fminf(m, __shfl_xor(m, 4));
                m = fminf(m, __shfl_xor(m, 8));
                rmin[i] = m;
            }
            const unsigned bb = (n & 1) ? bit1 : bit0;
#pragma unroll
            for (int i = 0; i < 4; ++i)
                if (v4[i] <= rmin[i] + EPS_SCREEN) bm[i][n >> 1] |= bb;
        }

        // ---- OR-reduce bitmaps + deliver to owner lanes (R12 verbatim) ----
#pragma unroll
        for (int i = 0; i < 4; ++i) {
#pragma unroll
            for (int w = 0; w < 4; ++w) {
                unsigned x = bm[i][w];
                x |= __shfl_xor(x, 1);
                x |= __shfl_xor(x, 2);
                x |= __shfl_xor(x, 4);
                x |= __shfl_xor(x, 8);
                bm[i][w] = x;
            }
        }
#pragma unroll
        for (int w = 0; w < 4; ++w) {
            unsigned t0 = __shfl(bm[0][w], sgl);
            unsigned t1 = __shfl(bm[1][w], sgl);
            unsigned t2 = __shfl(bm[2][w], sgl);
            unsigned t3 = __shfl(bm[3][w], sgl);
            unsigned vsel = (r3 == 0) ? t0 : (r3 == 1) ? t1 : (r3 == 2) ? t2 : t3;
            if ((lane >> 4) == T) mybm[w] = vsel;
        }
    }

    // ---- exact re-eval of candidates, frozen np arithmetic (ascending k, strict <)
    float best = 3.4e38f; int bi = 0;
    for (int w = 0; w < 4; ++w) {
        unsigned u = mybm[w];
        while (u) {
            const int k = (w << 5) + __builtin_ctz(u);
            u &= u - 1;
            const float4* cr = (const float4*)(cbg + (k << 6));
            float acc = 0.f;
#pragma unroll
            for (int q = 0; q < 16; ++q) {
                float4 cv = cr[q];
                acc = fmaf(cv.x, z[4*q + 0], acc);
                acc = fmaf(cv.y, z[4*q + 1], acc);
                acc = fmaf(cv.z, z[4*q + 2], acc);
                acc = fmaf(cv.w, z[4*q + 3], acc);
            }
            float dist = (sum_rr - 2.0f*acc) + ng[k];
            if (dist < best) { best = dist; bi = k; }
        }
    }
    __syncthreads();                             // belt-and-braces phase fence
    return bi;
}

__global__ __launch_bounds__(256) void rvq_main(
    const float* __restrict__ mel,
    const float* __restrict__ b_in,
    const float* __restrict__ cb0,
    const float* __restrict__ cb1,
    const float* __restrict__ b_out,
    const float* __restrict__ ws,
    float* __restrict__ out_mel,
    float* __restrict__ out_idx)
{
#pragma clang fp contract(off)
    const float* __restrict__ n0g = ws + WS_N0;
    const float* __restrict__ n1g = ws + WS_N1;
    const float* __restrict__ T0  = ws + WS_T0;
    const float* __restrict__ T1  = ws + WS_T1;

    __shared__ unsigned tab[8192];           // 32 KB: WT (f32) -> cb packed splits

    const int tid = threadIdx.x;
    const int b = blockIdx.x * 256 + tid;

    // ---- stage WT ----
    {
        float4* s4 = reinterpret_cast<float4*>(tab);
        const float4* src = reinterpret_cast<const float4*>(ws + WS_WT);
#pragma unroll
        for (int i = 0; i < 8; ++i) s4[i*256 + tid] = src[i*256 + tid];
    }
    __syncthreads();

    // ---- z = mel @ W_in^T + b_in (frozen R3 order) ----
    float z[DIM];
#pragma unroll
    for (int d = 0; d < DIM; ++d) z[d] = 0.f;

    const float4* melr = reinterpret_cast<const float4*>(mel + (size_t)b * MEL_BINS);
    const float4* s4c = reinterpret_cast<const float4*>(tab);
    for (int jc = 0; jc < MEL_BINS / 4; ++jc) {
        float4 m4 = melr[jc];
#pragma unroll
        for (int seg = 0; seg < 4; ++seg) {
            float mj = (seg == 0) ? m4.x : (seg == 1) ? m4.y : (seg == 2) ? m4.z : m4.w;
            const float4* w4 = s4c + (jc*4 + seg)*16;
#pragma unroll
            for (int q = 0; q < 16; ++q) {
                float4 wv = w4[q];
                z[4*q + 0] = fmaf(wv.x, mj, z[4*q + 0]);
                z[4*q + 1] = fmaf(wv.y, mj, z[4*q + 1]);
                z[4*q + 2] = fmaf(wv.z, mj, z[4*q + 2]);
                z[4*q + 3] = fmaf(wv.w, mj, z[4*q + 3]);
            }
        }
    }
#pragma unroll
    for (int d = 0; d < DIM; ++d) z[d] = z[d] + b_in[d];

    // ---- sum_rr (np pairwise, frozen) ----
    float s0 = z[0]*z[0], s1 = z[1]*z[1], s2 = z[2]*z[2], s3 = z[3]*z[3];
    float s4r = z[4]*z[4], s5 = z[5]*z[5], s6 = z[6]*z[6], s7 = z[7]*z[7];
#pragma unroll
    for (int i = 8; i < 64; i += 8) {
        s0 += z[i+0]*z[i+0]; s1 += z[i+1]*z[i+1];
        s2 += z[i+2]*z[i+2]; s3 += z[i+3]*z[i+3];
        s4r += z[i+4]*z[i+4]; s5 += z[i+5]*z[i+5];
        s6 += z[i+6]*z[i+6]; s7 += z[i+7]*z[i+7];
    }
    float sum_rr = ((s0 + s1) + (s2 + s3)) + ((s4r + s5) + (s6 + s7));

    // ================= codebook 0 =================
    const int i0 = vq_step(cb0, n0g, tab, z, sum_rr, tid);

    // ---- residual = z - cb0[i0] (frozen sub) ----
    {
        const float* cc = cb0 + (size_t)i0 * DIM;
#pragma unroll
        for (int d = 0; d < DIM; ++d) z[d] = z[d] - cc[d];
    }
    // ---- sum_rr' (np pairwise, frozen) ----
    s0 = z[0]*z[0]; s1 = z[1]*z[1]; s2 = z[2]*z[2]; s3 = z[3]*z[3];
    s4r = z[4]*z[4]; s5 = z[5]*z[5]; s6 = z[6]*z[6]; s7 = z[7]*z[7];
#pragma unroll
    for (int i = 8; i < 64; i += 8) {
        s0 += z[i+0]*z[i+0]; s1 += z[i+1]*z[i+1];
        s2 += z[i+2]*z[i+2]; s3 += z[i+3]*z[i+3];
        s4r += z[i+4]*z[i+4]; s5 += z[i+5]*z[i+5];
        s6 += z[i+6]*z[i+6]; s7 += z[i+7]*z[i+7];
    }
    sum_rr = ((s0 + s1) + (s2 + s3)) + ((s4r + s5) + (s6 + s7));

    // ================= codebook 1 =================
    const int i1 = vq_step(cb1, n1g, tab, z, sum_rr, tid);

    // ---- decode: out = T0[i0] + T1[i1] + b_out ----
    const float4* t0r = reinterpret_cast<const float4*>(T0 + (size_t)i0 * MEL_BINS);
    const float4* t1r = reinterpret_cast<const float4*>(T1 + (size_t)i1 * MEL_BINS);
    float4* outr = reinterpret_cast<float4*>(out_mel + (size_t)b * MEL_BINS);
#pragma unroll 4
    for (int q = 0; q < MEL_BINS / 4; ++q) {
        float4 a = t0r[q], cc = t1r[q];
        float4 o;
        o.x = a.x + cc.x + b_out[4*q + 0];
        o.y = a.y + cc.y + b_out[4*q + 1];
        o.z = a.z + cc.z + b_out[4*q + 2];
        o.w = a.w + cc.w + b_out[4*q + 3];
        outr[q] = o;
    }

    out_idx[2*(size_t)b + 0] = (float)i0;
    out_idx[2*(size_t)b + 1] = (float)i1;
}

extern "C" void kernel_launch(void* const* d_in, const int* in_sizes, int n_in,
                              void* d_out, int out_size, void* d_ws, size_t ws_size,
                              hipStream_t stream)
{
    const float* mel   = (const float*)d_in[0];
    const float* W_in  = (const float*)d_in[1];
    const float* b_in  = (const float*)d_in[2];
    const float* cb0   = (const float*)d_in[3];
    const float* cb1   = (const float*)d_in[4];
    const float* W_out = (const float*)d_in[5];
    const float* b_out = (const float*)d_in[6];

    float* ws      = (float*)d_ws;                 // 164864 bytes used
    float* out_mel = (float*)d_out;
    float* out_idx = (float*)d_out + (size_t)B_ROWS * MEL_BINS;

    rvq_precomp<<<(WS_TOT + 255) / 256, 256, 0, stream>>>(W_in, cb0, cb1, W_out, ws);
    rvq_main<<<B_ROWS / 256, 256, 0, stream>>>(mel, b_in, cb0, cb1, b_out, ws,
                                               out_mel, out_idx);
}

// Round 16
// 516.535 us; speedup vs baseline: 1.4736x; 1.4736x over previous
//
#include <hip/hip_runtime.h>
#include <hip/hip_bf16.h>

#define B_ROWS   524288
#define MEL_BINS 128
#define DIM      64
#define KCODES   128

// ---------------- workspace layout (floats) ----------------
// WT [128*64]  : W_in^T, WT[j*64+d] = W_in[d*128+j]
// P0 [8*1024]  : cb0 16-k panels, P0[c*1024 + d*16 + t] = cb0[(c*16+t)*64 + d]
// P1 [8*1024]  : cb1 panels
// n0,n1 [128]  : np pairwise ||c_k||^2
// T0,T1 [128*128] : cb @ W_out^T
#define WS_WT 0
#define WS_P0 (WS_WT + MEL_BINS*DIM)        // 8192
#define WS_P1 (WS_P0 + DIM*KCODES)          // 16384
#define WS_N0 (WS_P1 + DIM*KCODES)          // 24576
#define WS_N1 (WS_N0 + KCODES)              // 24704
#define WS_T0 (WS_N1 + KCODES)              // 24832
#define WS_T1 (WS_T0 + KCODES*MEL_BINS)     // 41216
#define WS_TOT (WS_T1 + KCODES*MEL_BINS)    // 57600 floats

// numpy pairwise_sum (scalar path) emulation for n=64 of v[d]*v[d].
__device__ __forceinline__ float np_pairwise64_sq(const float* v) {
#pragma clang fp contract(off)
    float r0 = v[0]*v[0], r1 = v[1]*v[1], r2 = v[2]*v[2], r3 = v[3]*v[3];
    float r4 = v[4]*v[4], r5 = v[5]*v[5], r6 = v[6]*v[6], r7 = v[7]*v[7];
#pragma unroll
    for (int i = 8; i < 64; i += 8) {
        r0 += v[i+0]*v[i+0]; r1 += v[i+1]*v[i+1];
        r2 += v[i+2]*v[i+2]; r3 += v[i+3]*v[i+3];
        r4 += v[i+4]*v[i+4]; r5 += v[i+5]*v[i+5];
        r6 += v[i+6]*v[i+6]; r7 += v[i+7]*v[i+7];
    }
    return ((r0 + r1) + (r2 + r3)) + ((r4 + r5) + (r6 + r7));
}

__global__ __launch_bounds__(256) void rvq_precomp(
    const float* __restrict__ W_in, const float* __restrict__ cb0,
    const float* __restrict__ cb1, const float* __restrict__ W_out,
    float* __restrict__ ws)
{
#pragma clang fp contract(off)
    float* WT = ws + WS_WT;
    float* P0 = ws + WS_P0;
    float* P1 = ws + WS_P1;
    float* n0 = ws + WS_N0;
    float* n1 = ws + WS_N1;
    float* T0 = ws + WS_T0;
    float* T1 = ws + WS_T1;

    int tid = blockIdx.x * 256 + threadIdx.x;
    if (tid < 16384) {                       // T0[i][m] (mel path: loose threshold)
        int i = tid >> 7, m = tid & 127;
        double a = 0.0;
        for (int d = 0; d < DIM; ++d)
            a = fma((double)cb0[i*DIM + d], (double)W_out[m*DIM + d], a);
        T0[tid] = (float)a;
    } else if (tid < 32768) {                // T1[i][m]
        int t = tid - 16384;
        int i = t >> 7, m = t & 127;
        double a = 0.0;
        for (int d = 0; d < DIM; ++d)
            a = fma((double)cb1[i*DIM + d], (double)W_out[m*DIM + d], a);
        T1[t] = (float)a;
    } else if (tid < 40960) {                // WT[j][d] = W_in[d][j]
        int t = tid - 32768;
        int j = t >> 6, d = t & 63;
        WT[t] = W_in[d*MEL_BINS + j];
    } else if (tid < 41216) {                // n0 / n1 (exact np pairwise)
        int t = tid - 40960;
        const float* cb = (t & 128) ? cb1 : cb0;
        float*       nn = (t & 128) ? n1  : n0;
        int k = t & 127;
        nn[k] = np_pairwise64_sq(cb + k*DIM);
    } else if (tid < 49408) {                // P0 panels
        int e = tid - 41216;
        int c = e >> 10, rem = e & 1023;
        int d = rem >> 4, t = rem & 15;
        P0[e] = cb0[(c*16 + t)*DIM + d];
    } else if (tid < 57600) {                // P1 panels
        int e = tid - 49408;
        int c = e >> 10, rem = e & 1023;
        int d = rem >> 4, t = rem & 15;
        P1[e] = cb1[(c*16 + t)*DIM + d];
    }
}

// 1 row/thread. 16 KB LDS (halved tables staged in sequence) + wave-uniform
// ds_read_b128 broadcasts + d-outer acc[16] dot loops (ILP=16 across k).
// PER-VALUE FP OP ORDER IS BIT-IDENTICAL to the R3-verified np-f32 emulation:
// each z_d is an ascending-j fused chain; each dot_k is a single accumulator
// over ascending d; squares use the np 8-acc pairwise tree; argmin scans
// ascending k with strict <. DO NOT REORDER.
__global__ __launch_bounds__(256) void rvq_main(
    const float* __restrict__ mel,
    const float* __restrict__ b_in,
    const float* __restrict__ cb0,
    const float* __restrict__ cb1,
    const float* __restrict__ b_out,
    const float* __restrict__ ws,
    float* __restrict__ out_mel,
    float* __restrict__ out_idx)
{
#pragma clang fp contract(off)
    const float* __restrict__ n0g = ws + WS_N0;
    const float* __restrict__ n1g = ws + WS_N1;
    const float* __restrict__ T0  = ws + WS_T0;
    const float* __restrict__ T1  = ws + WS_T1;

    __shared__ float slds[4096];             // 16 KB staging buffer
    float4* sw4 = reinterpret_cast<float4*>(slds);
    const float4* sl4 = reinterpret_cast<const float4*>(slds);

    const int tid = threadIdx.x;
    const int b = blockIdx.x * 256 + tid;
    const float4* melr = reinterpret_cast<const float4*>(mel + (size_t)b * MEL_BINS);

    float z[DIM];
#pragma unroll
    for (int d = 0; d < DIM; ++d) z[d] = 0.f;

    // ======== z-GEMM in two j-halves (WT staged 16 KB at a time) ========
    const float4* wt4 = reinterpret_cast<const float4*>(ws + WS_WT);
    for (int h = 0; h < 2; ++h) {
        __syncthreads();
#pragma unroll
        for (int i = 0; i < 4; ++i) sw4[i*256 + tid] = wt4[h*1024 + i*256 + tid];
        __syncthreads();

        for (int jc = 0; jc < 16; ++jc) {    // global j = (h*16+jc)*4 + seg, ascending
            float4 m4 = melr[h*16 + jc];
#pragma unroll
            for (int seg = 0; seg < 4; ++seg) {
                float mj = (seg == 0) ? m4.x : (seg == 1) ? m4.y : (seg == 2) ? m4.z : m4.w;
                const float4* w4 = sl4 + (jc*4 + seg)*16;   // uniform -> broadcast
#pragma unroll
                for (int q = 0; q < 16; ++q) {
                    float4 wv = w4[q];
                    z[4*q + 0] = fmaf(wv.x, mj, z[4*q + 0]);
                    z[4*q + 1] = fmaf(wv.y, mj, z[4*q + 1]);
                    z[4*q + 2] = fmaf(wv.z, mj, z[4*q + 2]);
                    z[4*q + 3] = fmaf(wv.w, mj, z[4*q + 3]);
                }
            }
        }
    }
#pragma unroll
    for (int d = 0; d < DIM; ++d) z[d] = z[d] + b_in[d];     // frozen bias add

    // ---- sum_rr (np pairwise, frozen) ----
    float s0 = z[0]*z[0], s1 = z[1]*z[1], s2 = z[2]*z[2], s3 = z[3]*z[3];
    float s4 = z[4]*z[4], s5 = z[5]*z[5], s6 = z[6]*z[6], s7 = z[7]*z[7];
#pragma unroll
    for (int i = 8; i < 64; i += 8) {
        s0 += z[i+0]*z[i+0]; s1 += z[i+1]*z[i+1];
        s2 += z[i+2]*z[i+2]; s3 += z[i+3]*z[i+3];
        s4 += z[i+4]*z[i+4]; s5 += z[i+5]*z[i+5];
        s6 += z[i+6]*z[i+6]; s7 += z[i+7]*z[i+7];
    }
    float sum_rr = ((s0 + s1) + (s2 + s3)) + ((s4 + s5) + (s6 + s7));

    // ======== codebook 0: k-halves staged, chunks of 16 k, acc[16] ILP ========
    const float4* p04 = reinterpret_cast<const float4*>(ws + WS_P0);
    float best0 = 3.4e38f; int i0 = 0;
    for (int h = 0; h < 2; ++h) {
        __syncthreads();
#pragma unroll
        for (int i = 0; i < 4; ++i) sw4[i*256 + tid] = p04[h*1024 + i*256 + tid];
        __syncthreads();

        for (int q = 0; q < 4; ++q) {        // chunk: k = h*64 + q*16 + t
            const float4* pan = sl4 + q*256; // 1024 floats per chunk
            float acc[16];
#pragma unroll
            for (int t = 0; t < 16; ++t) acc[t] = 0.f;
#pragma unroll
            for (int d = 0; d < DIM; ++d) {  // FULL unroll: z[d]/acc[t] static
                float4 p0 = pan[d*4 + 0];
                float4 p1 = pan[d*4 + 1];
                float4 p2 = pan[d*4 + 2];
                float4 p3 = pan[d*4 + 3];
                float zd = z[d];
                acc[ 0] = fmaf(p0.x, zd, acc[ 0]);
                acc[ 1] = fmaf(p0.y, zd, acc[ 1]);
                acc[ 2] = fmaf(p0.z, zd, acc[ 2]);
                acc[ 3] = fmaf(p0.w, zd, acc[ 3]);
                acc[ 4] = fmaf(p1.x, zd, acc[ 4]);
                acc[ 5] = fmaf(p1.y, zd, acc[ 5]);
                acc[ 6] = fmaf(p1.z, zd, acc[ 6]);
                acc[ 7] = fmaf(p1.w, zd, acc[ 7]);
                acc[ 8] = fmaf(p2.x, zd, acc[ 8]);
                acc[ 9] = fmaf(p2.y, zd, acc[ 9]);
                acc[10] = fmaf(p2.z, zd, acc[10]);
                acc[11] = fmaf(p2.w, zd, acc[11]);
                acc[12] = fmaf(p3.x, zd, acc[12]);
                acc[13] = fmaf(p3.y, zd, acc[13]);
                acc[14] = fmaf(p3.z, zd, acc[14]);
                acc[15] = fmaf(p3.w, zd, acc[15]);
            }
            const int kb = h*64 + q*16;
            const float* nk = n0g + kb;      // uniform -> s_load (tiny)
#pragma unroll
            for (int t = 0; t < 16; ++t) {   // ascending k, strict < (np.argmin)
                float dist = (sum_rr - 2.0f*acc[t]) + nk[t];
                if (dist < best0) { best0 = dist; i0 = kb + t; }
            }
        }
    }

    // ---- residual = z - cb0[i0] : per-lane global gather (L2-hot), frozen sub
    {
        const float* cc = cb0 + (size_t)i0 * DIM;
#pragma unroll
        for (int d = 0; d < DIM; ++d) z[d] = z[d] - cc[d];
    }

    // ---- sum_rr' (np pairwise, frozen) ----
    s0 = z[0]*z[0]; s1 = z[1]*z[1]; s2 = z[2]*z[2]; s3 = z[3]*z[3];
    s4 = z[4]*z[4]; s5 = z[5]*z[5]; s6 = z[6]*z[6]; s7 = z[7]*z[7];
#pragma unroll
    for (int i = 8; i < 64; i += 8) {
        s0 += z[i+0]*z[i+0]; s1 += z[i+1]*z[i+1];
        s2 += z[i+2]*z[i+2]; s3 += z[i+3]*z[i+3];
        s4 += z[i+4]*z[i+4]; s5 += z[i+5]*z[i+5];
        s6 += z[i+6]*z[i+6]; s7 += z[i+7]*z[i+7];
    }
    sum_rr = ((s0 + s1) + (s2 + s3)) + ((s4 + s5) + (s6 + s7));

    // ======== codebook 1 ========
    const float4* p14 = reinterpret_cast<const float4*>(ws + WS_P1);
    float best1 = 3.4e38f; int i1 = 0;
    for (int h = 0; h < 2; ++h) {
        __syncthreads();
#pragma unroll
        for (int i = 0; i < 4; ++i) sw4[i*256 + tid] = p14[h*1024 + i*256 + tid];
        __syncthreads();

        for (int q = 0; q < 4; ++q) {
            const float4* pan = sl4 + q*256;
            float acc[16];
#pragma unroll
            for (int t = 0; t < 16; ++t) acc[t] = 0.f;
#pragma unroll
            for (int d = 0; d < DIM; ++d) {
                float4 p0 = pan[d*4 + 0];
                float4 p1 = pan[d*4 + 1];
                float4 p2 = pan[d*4 + 2];
                float4 p3 = pan[d*4 + 3];
                float zd = z[d];
                acc[ 0] = fmaf(p0.x, zd, acc[ 0]);
                acc[ 1] = fmaf(p0.y, zd, acc[ 1]);
                acc[ 2] = fmaf(p0.z, zd, acc[ 2]);
                acc[ 3] = fmaf(p0.w, zd, acc[ 3]);
                acc[ 4] = fmaf(p1.x, zd, acc[ 4]);
                acc[ 5] = fmaf(p1.y, zd, acc[ 5]);
                acc[ 6] = fmaf(p1.z, zd, acc[ 6]);
                acc[ 7] = fmaf(p1.w, zd, acc[ 7]);
                acc[ 8] = fmaf(p2.x, zd, acc[ 8]);
                acc[ 9] = fmaf(p2.y, zd, acc[ 9]);
                acc[10] = fmaf(p2.z, zd, acc[10]);
                acc[11] = fmaf(p2.w, zd, acc[11]);
                acc[12] = fmaf(p3.x, zd, acc[12]);
                acc[13] = fmaf(p3.y, zd, acc[13]);
                acc[14] = fmaf(p3.z, zd, acc[14]);
                acc[15] = fmaf(p3.w, zd, acc[15]);
            }
            const int kb = h*64 + q*16;
            const float* nk = n1g + kb;
#pragma unroll
            for (int t = 0; t < 16; ++t) {
                float dist = (sum_rr - 2.0f*acc[t]) + nk[t];
                if (dist < best1) { best1 = dist; i1 = kb + t; }
            }
        }
    }

    // ---- decode: out = T0[i0] + T1[i1] + b_out ----
    const float4* t0r = reinterpret_cast<const float4*>(T0 + (size_t)i0 * MEL_BINS);
    const float4* t1r = reinterpret_cast<const float4*>(T1 + (size_t)i1 * MEL_BINS);
    float4* outr = reinterpret_cast<float4*>(out_mel + (size_t)b * MEL_BINS);
#pragma unroll 4
    for (int q = 0; q < MEL_BINS / 4; ++q) {
        float4 a = t0r[q], cc = t1r[q];
        float4 o;
        o.x = a.x + cc.x + b_out[4*q + 0];
        o.y = a.y + cc.y + b_out[4*q + 1];
        o.z = a.z + cc.z + b_out[4*q + 2];
        o.w = a.w + cc.w + b_out[4*q + 3];
        outr[q] = o;
    }

    out_idx[2*(size_t)b + 0] = (float)i0;
    out_idx[2*(size_t)b + 1] = (float)i1;
}

extern "C" void kernel_launch(void* const* d_in, const int* in_sizes, int n_in,
                              void* d_out, int out_size, void* d_ws, size_t ws_size,
                              hipStream_t stream)
{
    const float* mel   = (const float*)d_in[0];
    const float* W_in  = (const float*)d_in[1];
    const float* b_in  = (const float*)d_in[2];
    const float* cb0   = (const float*)d_in[3];
    const float* cb1   = (const float*)d_in[4];
    const float* W_out = (const float*)d_in[5];
    const float* b_out = (const float*)d_in[6];

    float* ws      = (float*)d_ws;                 // 230400 bytes used
    float* out_mel = (float*)d_out;
    float* out_idx = (float*)d_out + (size_t)B_ROWS * MEL_BINS;

    rvq_precomp<<<(WS_TOT + 255) / 256, 256, 0, stream>>>(W_in, cb0, cb1, W_out, ws);
    rvq_main<<<B_ROWS / 256, 256, 0, stream>>>(mel, b_in, cb0, cb1, b_out, ws,
                                               out_mel, out_idx);
}